// Round 11
// baseline (141.720 us; speedup 1.0000x reference)
//
#include <hip/hip_runtime.h>
#include <hip/hip_bf16.h>
#include <cstddef>
#include <cstdint>

typedef __attribute__((ext_vector_type(8))) short short8_t;   // 8 bf16 (4 VGPRs)
typedef __attribute__((ext_vector_type(4))) float f32x4;
typedef __attribute__((ext_vector_type(2))) float f32x2;
typedef unsigned short ushort4a __attribute__((ext_vector_type(4))); // 8B

// Per-wave fences: forbid compiler motion of memory ops and drain the HW
// queue. Cross-lane LDS deps and LDS-DMA writes are invisible to per-thread
// dependence analysis.
#define WAVE_FENCE()                                        \
  do {                                                      \
    asm volatile("s_waitcnt lgkmcnt(0)" ::: "memory");      \
    __builtin_amdgcn_sched_barrier(0);                      \
  } while (0)
#define VM_FENCE()                                          \
  do {                                                      \
    asm volatile("s_waitcnt vmcnt(0)" ::: "memory");        \
    __builtin_amdgcn_sched_barrier(0);                      \
  } while (0)

namespace {
constexpr int T = 2048;
constexpr int NB = 16;
constexpr int NJ = 53;
constexpr int NN = 18;              // names
constexpr int TTILE = 256;          // R16: per-block tax amortization; NT stores keep L2 reuse
constexpr int NTILES = T / TTILE;   // 8
constexpr int MT_LIN = 17;          // ceil(258/16) m-tiles for linear phase
constexpr int MT_CNV = 16;          // conv m-tiles
constexpr int HROWS = TTILE + 2;    // 258 h rows actually consumed by conv
constexpr int HSTR = 36;            // ushort stride per h row (72B, 8B-aligned rows)
// SSTR=38 (R15): g-stride 152B == 24 mod 32 dwords -> staging writes 2-way (free).
constexpr int SSTR = 38;            // f32 stride of store-staging tile (152B)
constexpr int NITEMS = NB * NTILES; // 128 (b,tile) items per joint j
constexpr int NPERS = 1024;         // persistent blocks: exactly 4 per CU
}

__constant__ int c_name_ids[NJ] = {
    0,1,2,3,4,1,2,3,4,5,6,7,8,9,10,11,12,13,14,15,16,14,15,16,14,15,16,
    14,15,16,14,15,16,10,11,12,13,14,15,16,14,15,16,14,15,16,14,15,16,
    14,15,16,17};

// Precomputed weight fragments: [name][ks|k][nt][hi/lo][lane]
__device__ short8_t g_linfrag[NN][2][2][2][64];   // 147 KB
__device__ short8_t g_convfrag[NN][3][2][2][64];  // 221 KB

__device__ __forceinline__ unsigned short f2bf(float f) {
  return __builtin_bit_cast(unsigned short, __float2bfloat16(f));
}
__device__ __forceinline__ float bf2f(unsigned short u) {
  return __bfloat162float(__builtin_bit_cast(__hip_bfloat16, u));
}

// slot map: slot(g,e) -> k = 4g + (e&3) + 16*(e>>2); used identically for A and B
// fragments, so any true HW k-map yields a correct dot product.

__global__ __launch_bounds__(64)
void prep_weights(const float* __restrict__ lin_w,
                  const float* __restrict__ conv_w)
{
  const int n = blockIdx.x;
  const int l = threadIdx.x;
  const int r = l & 15;
  const int g = l >> 4;
#pragma unroll
  for (int ks = 0; ks < 2; ++ks)
#pragma unroll
    for (int nt = 0; nt < 2; ++nt) {
      short8_t hi8, lo8;
#pragma unroll
      for (int e = 0; e < 8; ++e) {
        const int kk = 4 * g + (e & 3) + 16 * (e >> 2);
        const float w = lin_w[((size_t)n * 64 + ks * 32 + kk) * 32 + r + 16 * nt];
        const unsigned short h = f2bf(w);
        hi8[e] = (short)h;
        lo8[e] = (short)f2bf(w - bf2f(h));
      }
      g_linfrag[n][ks][nt][0][l] = hi8;
      g_linfrag[n][ks][nt][1][l] = lo8;
    }
#pragma unroll
  for (int k = 0; k < 3; ++k)
#pragma unroll
    for (int nt = 0; nt < 2; ++nt) {
      short8_t hi8, lo8;
#pragma unroll
      for (int e = 0; e < 8; ++e) {
        const int i = 4 * g + (e & 3) + 16 * (e >> 2);
        const float w = conv_w[(((size_t)n * 32 + r + 16 * nt) * 32 + i) * 3 + k];
        const unsigned short h = f2bf(w);
        hi8[e] = (short)h;
        lo8[e] = (short)f2bf(w - bf2f(h));
      }
      g_convfrag[n][k][nt][0][l] = hi8;
      g_convfrag[n][k][nt][1][l] = lo8;
    }
}

// R23 = R21 made PERSISTENT: 1024 blocks (exactly 4/CU), block B owns joint
// j = floor(53B/1024) and processes ~6-7 of that j's 128 (b,tile) items.
//   - weight fragments (BOTH sets) loaded ONCE per block: j is constant.
//     ~80 VGPR parked + ~35 working < 128 budget of (256,4). WRITE_SIZE is
//     the spill falsifier (fired 3x on launch-bounds experiments).
//   - cross-item DMA prefetch: at conv end, issue next item's first feat
//     tile; it flies during the barrier join -> per-item pipeline fill ~0.
//   - raw s_barrier + explicit per-wave lgkm fences instead of __syncthreads:
//     the compiler's __syncthreads drains vmcnt(0) before s_barrier, which
//     would kill the prefetch (the m97 barrier-drain stall). LDS hazards:
//     every wave drains lgkm (h-writes / staging reads) before its arrival.
//   - 2 raw barriers per item replace 1 __syncthreads + block launch/teardown.
// Fixed-tax model (R13: 13.25 rounds = 87.5us, R16: 6.625 = 77.7us -> tax
// ~1.48us/round): persistence attacks the tax itself, not the round count.
// Kept from R21: dropped input-residual, SSTR=38, NT stores, LDS-DMA
// transport, shallow depth-1 pipeline (R22 proved depth-2 at 3 blk/CU loses).
__global__ __launch_bounds__(256, 4)
void fused_rcb_mfma(const float* __restrict__ x,
                    const float* __restrict__ lin_b,
                    const float* __restrict__ conv_b,
                    float* __restrict__ out)
{
  __shared__ __align__(16) unsigned short s_hi[HROWS * HSTR];  // 18.6 KB
  __shared__ __align__(16) char s_feat[4][4096];               // 16 KB: feat stage (lin) / store stage (conv)

  const int B = blockIdx.x;
  // Block -> joint mapping: ~19-20 consecutive blocks share one j; they split
  // that j's 128 items by stride nB. Bijective: sum(nB) over j = 1024, and
  // {local + k*nB} for local in [0,nB) tiles [0,128).
  const int jB    = (53 * B) >> 10;                  // floor(53B/1024)
  const int lo    = (jB * 1024 + 52) / 53;           // ceil(1024*jB/53)
  const int hi    = ((jB + 1) * 1024 + 52) / 53;
  const int nB    = hi - lo;                         // blocks sharing this j
  const int local = B - lo;

  const int j   = jB;
  const int nid = c_name_ids[j];
  const int jp  = (j > 0) ? (j - 1) : 0;

  const int tid = threadIdx.x;
  const int wv = tid >> 6;        // wave 0..3
  const int l  = tid & 63;
  const int r  = l & 15;          // M/N index within fragment
  const int g  = l >> 4;          // k-slot group

  char* featc = s_feat[wv];       // wave-private

  // Issue the 4 LDS-DMA loads for m-tile mt of the item at (xj,xp,t0).
  // Each instruction a contiguous 1KB (8 full lines); global source byte is
  // inverse-XOR-swizzled so LDS holds the swizzled layout (rule #21).
  auto issue_feat = [&](const float* xj_b, const float* xp_b, int t0_, int mt) {
#pragma unroll
    for (int j2 = 0; j2 < 2; ++j2) {
      const float* jb = j2 ? xp_b : xj_b;
#pragma unroll
      for (int i = 0; i < 2; ++i) {
        const int row = i * 8 + (l >> 3);
        int t = t0_ + mt * 16 + row - 1;       // reflect padding in time
        if (t < 0) t = -t;
        if (t > T - 1) t = 2 * (T - 1) - t;
        const char* src = reinterpret_cast<const char*>(jb + (size_t)t * (NJ * 32))
                          + (((l & 7) * 16) ^ ((row & 7) << 4));
        __builtin_amdgcn_global_load_lds(
            (const __attribute__((address_space(1))) unsigned int*)src,
            (__attribute__((address_space(3))) unsigned int*)(&s_feat[wv][j2 * 2048 + i * 1024]),
            16, 0, 0);
      }
    }
  };

  // Item -> (b,tile) bases.
  int b_cur, t0;
  const float *xj_base, *xp_base;
  auto set_bases = [&](int s) {
    b_cur = s >> 3;
    t0 = (s & 7) * TTILE;
    xj_base = x + ((size_t)b_cur * T * NJ + j) * 32;
    xp_base = x + ((size_t)b_cur * T * NJ + jp) * 32;
  };

  // ---- prologue: first item's first tile in flight, then weight loads ----
  set_bases(local);
  issue_feat(xj_base, xp_base, t0, wv);

  // Both weight sets loaded ONCE per block (j constant). Coalesced 16B/lane.
  short8_t blh[2][2], bll[2][2];
#pragma unroll
  for (int ks = 0; ks < 2; ++ks)
#pragma unroll
    for (int nt = 0; nt < 2; ++nt) {
      blh[ks][nt] = g_linfrag[nid][ks][nt][0][l];
      bll[ks][nt] = g_linfrag[nid][ks][nt][1][l];
    }
  short8_t bch[3][2], bcl[3][2];
#pragma unroll
  for (int k = 0; k < 3; ++k)
#pragma unroll
    for (int nt = 0; nt < 2; ++nt) {
      bch[k][nt] = g_convfrag[nid][k][nt][0][l];
      bcl[k][nt] = g_convfrag[nid][k][nt][1][l];
    }
  const float lb0 = lin_b[nid * 32 + r];
  const float lb1 = lin_b[nid * 32 + r + 16];
  const float cb0 = conv_b[nid * 32 + r];
  const float cb1 = conv_b[nid * 32 + r + 16];

  // ---------------- persistent item loop ----------------
  for (int s = local; s < NITEMS; s += nB) {
    const int  snx      = s + nB;
    const bool has_next = snx < NITEMS;

    // ---- linear phase: h = relu(feat @ W + b) ----
    for (int mt = wv; mt < MT_LIN; mt += 4) {
      VM_FENCE();   // feat[mt] landed (also drains weight loads on 1st iter)

      f32x4 a0[2], a1[2];
#pragma unroll
      for (int ks = 0; ks < 2; ++ks) {
        const char* fw = featc + ks * 2048 + r * 128;
        a0[ks] = *reinterpret_cast<const f32x4*>(fw + ((16 * g) ^ ((r & 7) << 4)));
        a1[ks] = *reinterpret_cast<const f32x4*>(fw + ((64 + 16 * g) ^ ((r & 7) << 4)));
      }
      WAVE_FENCE();                       // feat reads retired -> buffer reusable
      if (mt + 4 < MT_LIN) issue_feat(xj_base, xp_base, t0, mt + 4);

      // R21: input hi-part only (RTZ top16); residual dropped.
      short8_t ah[2];
#pragma unroll
      for (int ks = 0; ks < 2; ++ks) {
#pragma unroll
        for (int e = 0; e < 8; ++e) {
          const float f = (e < 4) ? a0[ks][e] : a1[ks][e - 4];
          ah[ks][e] = (short)(unsigned short)(__builtin_bit_cast(uint32_t, f) >> 16);
        }
      }

#pragma unroll
      for (int nt = 0; nt < 2; ++nt) {
        const float lb = nt ? lb1 : lb0;
        f32x4 acc = {lb, lb, lb, lb};
#pragma unroll
        for (int ks = 0; ks < 2; ++ks) {
          acc = __builtin_amdgcn_mfma_f32_16x16x32_bf16(ah[ks], blh[ks][nt], acc, 0, 0, 0);
          acc = __builtin_amdgcn_mfma_f32_16x16x32_bf16(ah[ks], bll[ks][nt], acc, 0, 0, 0);
        }
        // C/D layout (m89): row = 4g+q, col = r
#pragma unroll
        for (int q = 0; q < 4; ++q) {
          const int hrow = mt * 16 + 4 * g + q;
          if (hrow < HROWS)   // only mt=16 tail rows are out of range
            s_hi[hrow * HSTR + r + 16 * nt] = f2bf(fmaxf(acc[q], 0.0f));
        }
      }
    }

    // lin -> conv join: each wave drains its own h ds_writes, then raw
    // barrier (no vmcnt drain -- nothing in flight here anyway).
    WAVE_FENCE();
    __builtin_amdgcn_s_barrier();

    // ---- conv phase: y[t] = sum_k h[t+k-1] @ cw[k] + cb ----
    float* st = reinterpret_cast<float*>(featc);   // alias: feat buffer dead in conv
    for (int mt = wv; mt < MT_CNV; mt += 4) {
      const int m0 = mt * 16;
      short8_t ah[3];
#pragma unroll
      for (int k = 0; k < 3; ++k) {
        const int arow = m0 + r + k;
        const ushort4a u0 = *reinterpret_cast<const ushort4a*>(&s_hi[arow * HSTR + 4 * g]);
        const ushort4a u1 = *reinterpret_cast<const ushort4a*>(&s_hi[arow * HSTR + 16 + 4 * g]);
        short8_t hi8;
#pragma unroll
        for (int e = 0; e < 4; ++e) {
          hi8[e] = (short)u0[e];
          hi8[e + 4] = (short)u1[e];
        }
        ah[k] = hi8;
      }

      f32x4 accv[2];
#pragma unroll
      for (int nt = 0; nt < 2; ++nt) {
        const float cb = nt ? cb1 : cb0;
        f32x4 acc = {cb, cb, cb, cb};
#pragma unroll
        for (int k = 0; k < 3; ++k) {
          acc = __builtin_amdgcn_mfma_f32_16x16x32_bf16(ah[k], bch[k][nt], acc, 0, 0, 0);
          acc = __builtin_amdgcn_mfma_f32_16x16x32_bf16(ah[k], bcl[k][nt], acc, 0, 0, 0);
        }
        accv[nt] = acc;
      }

      // ---- wide-store epilogue: transpose acc through wave-private LDS ----
      WAVE_FENCE();   // WAR: previous m-tile's staging reads retired
#pragma unroll
      for (int nt = 0; nt < 2; ++nt)
#pragma unroll
        for (int q = 0; q < 4; ++q)
          st[(4 * g + q) * SSTR + r + 16 * nt] = accv[nt][q];
      WAVE_FENCE();   // RAW: staging writes visible to transposed reads

#pragma unroll
      for (int h2 = 0; h2 < 2; ++h2) {
        const int row = h2 * 8 + (l >> 3);          // 8-lane groups read one row
        const float* rp = st + row * SSTR + (l & 7) * 4;
        const f32x2 rd0 = *reinterpret_cast<const f32x2*>(rp);      // 8B reads keep
        const f32x2 rd1 = *reinterpret_cast<const f32x2*>(rp + 2);  // odd rows aligned
        f32x4 rd;
        rd[0] = rd0[0]; rd[1] = rd0[1]; rd[2] = rd1[0]; rd[3] = rd1[1];
        const int t = t0 + m0 + row;
        // Nontemporal: out is write-once; do not evict the L2-resident x columns.
        __builtin_nontemporal_store(rd, reinterpret_cast<f32x4*>(
            out + ((size_t)(b_cur * T + t) * NJ + j) * 32 + (l & 7) * 4));
      }
    }

    // ---- item epilogue: prefetch next item's first tile, then join ----
    if (has_next) {
      set_bases(snx);
      WAVE_FENCE();                       // staging reads retired before featc overwrite
      issue_feat(xj_base, xp_base, t0, wv);   // flies during barrier + next weights-free lin head
      // conv -> next-lin join: every wave has drained its s_hi reads (the
      // WAVE_FENCE above) before arrival; raw barrier does NOT drain vmcnt,
      // so the prefetch stays in flight (the whole point).
      __builtin_amdgcn_s_barrier();
    }
  }
}

extern "C" void kernel_launch(void* const* d_in, const int* in_sizes, int n_in,
                              void* d_out, int out_size, void* d_ws, size_t ws_size,
                              hipStream_t stream) {
  const float* x      = (const float*)d_in[0];
  const float* lin_w  = (const float*)d_in[1];
  const float* lin_b  = (const float*)d_in[2];
  const float* conv_w = (const float*)d_in[3];
  const float* conv_b = (const float*)d_in[4];
  float* out = (float*)d_out;

  prep_weights<<<dim3(NN), 64, 0, stream>>>(lin_w, conv_w);
  fused_rcb_mfma<<<dim3(NPERS), 256, 0, stream>>>(x, lin_b, conv_b, out);
}

// Round 12
// 80.764 us; speedup vs baseline: 1.7547x; 1.7547x over previous
//
#include <hip/hip_runtime.h>
#include <hip/hip_bf16.h>
#include <cstddef>
#include <cstdint>

typedef __attribute__((ext_vector_type(8))) short short8_t;   // 8 bf16 (4 VGPRs)
typedef __attribute__((ext_vector_type(4))) float f32x4;
typedef __attribute__((ext_vector_type(2))) float f32x2;
typedef unsigned short ushort4a __attribute__((ext_vector_type(4))); // 8B

// Per-wave fences: forbid compiler motion of memory ops and drain the HW
// queue. Cross-lane LDS deps and LDS-DMA writes are invisible to per-thread
// dependence analysis.
#define WAVE_FENCE()                                        \
  do {                                                      \
    asm volatile("s_waitcnt lgkmcnt(0)" ::: "memory");      \
    __builtin_amdgcn_sched_barrier(0);                      \
  } while (0)
#define VM_FENCE()                                          \
  do {                                                      \
    asm volatile("s_waitcnt vmcnt(0)" ::: "memory");        \
    __builtin_amdgcn_sched_barrier(0);                      \
  } while (0)

namespace {
constexpr int T = 2048;
constexpr int NB = 16;
constexpr int NJ = 53;
constexpr int NN = 18;              // names
constexpr int TTILE = 256;          // R16: per-block tax amortization; NT stores keep L2 reuse
constexpr int NTILES = T / TTILE;   // 8
constexpr int WROWS = 64;           // R24: contiguous out rows per wave
constexpr int LT_W = 5;             // lin tiles/wave (80 rows computed, 66 used)
constexpr int CT_W = 4;             // conv tiles/wave
constexpr int HREG = WROWS + 2;     // 66 h rows per wave-private region
constexpr int HSTR = 36;            // ushort stride per h row (72B, 8B-aligned rows)
// SSTR=38 (R15): g-stride 152B == 24 mod 32 dwords -> staging writes 2-way (free).
constexpr int SSTR = 38;            // f32 stride of store-staging tile (152B)
constexpr int NBLK = NB * NJ * NTILES;  // 6784
constexpr int XSPAN = NBLK / 8;         // 848 (bijective XCD swizzle)
}

__constant__ int c_name_ids[NJ] = {
    0,1,2,3,4,1,2,3,4,5,6,7,8,9,10,11,12,13,14,15,16,14,15,16,14,15,16,
    14,15,16,14,15,16,10,11,12,13,14,15,16,14,15,16,14,15,16,14,15,16,
    14,15,16,17};

// Precomputed weight fragments: [name][ks|k][nt][hi/lo][lane]
__device__ short8_t g_linfrag[NN][2][2][2][64];   // 147 KB
__device__ short8_t g_convfrag[NN][3][2][2][64];  // 221 KB

__device__ __forceinline__ unsigned short f2bf(float f) {
  return __builtin_bit_cast(unsigned short, __float2bfloat16(f));
}
__device__ __forceinline__ float bf2f(unsigned short u) {
  return __bfloat162float(__builtin_bit_cast(__hip_bfloat16, u));
}

// slot map: slot(g,e) -> k = 4g + (e&3) + 16*(e>>2); used identically for A and B
// fragments, so any true HW k-map yields a correct dot product.

__global__ __launch_bounds__(64)
void prep_weights(const float* __restrict__ lin_w,
                  const float* __restrict__ conv_w)
{
  const int n = blockIdx.x;
  const int l = threadIdx.x;
  const int r = l & 15;
  const int g = l >> 4;
#pragma unroll
  for (int ks = 0; ks < 2; ++ks)
#pragma unroll
    for (int nt = 0; nt < 2; ++nt) {
      short8_t hi8, lo8;
#pragma unroll
      for (int e = 0; e < 8; ++e) {
        const int kk = 4 * g + (e & 3) + 16 * (e >> 2);
        const float w = lin_w[((size_t)n * 64 + ks * 32 + kk) * 32 + r + 16 * nt];
        const unsigned short h = f2bf(w);
        hi8[e] = (short)h;
        lo8[e] = (short)f2bf(w - bf2f(h));
      }
      g_linfrag[n][ks][nt][0][l] = hi8;
      g_linfrag[n][ks][nt][1][l] = lo8;
    }
#pragma unroll
  for (int k = 0; k < 3; ++k)
#pragma unroll
    for (int nt = 0; nt < 2; ++nt) {
      short8_t hi8, lo8;
#pragma unroll
      for (int e = 0; e < 8; ++e) {
        const int i = 4 * g + (e & 3) + 16 * (e >> 2);
        const float w = conv_w[(((size_t)n * 32 + r + 16 * nt) * 32 + i) * 3 + k];
        const unsigned short h = f2bf(w);
        hi8[e] = (short)h;
        lo8[e] = (short)f2bf(w - bf2f(h));
      }
      g_convfrag[n][k][nt][0][l] = hi8;
      g_convfrag[n][k][nt][1][l] = lo8;
    }
}

// R24 = R21 with the block-wide __syncthreads DELETED via per-wave contiguous
// chunks. Wave w owns out rows [64w, 64w+64); its lin phase computes h local
// rows 0..65 (5 tiles, base t0+64w-1, tail guarded) into a WAVE-PRIVATE s_hi
// region; its conv phase reads only that region.
//   - no cross-wave coupling at all (barrier + straggle + 5/4/4/4 imbalance
//     gone; now exactly 5 lin + 4 conv tiles per wave)
//   - phase separation preserved: conv weights load AFTER lin (the R14/R18/
//     R19 spill trap stays closed; R23's locality trap avoided -- block
//     order unchanged)
//   - boundary h rows recomputed: 20 vs 17 lin tiles (+18% lin MFMA; extra
//     reads are L2-resident neighbor rows)
//   - LDS 19.0+16 = 35.0KB (= R21 class) -> same occupancy
// Kept from R21: dropped input-residual, SSTR=38, NT stores, LDS-DMA
// transport, depth-1 pipeline (R22: depth-2 loses), (256,4) bounds.
__global__ __launch_bounds__(256, 4)
void fused_rcb_mfma(const float* __restrict__ x,
                    const float* __restrict__ lin_b,
                    const float* __restrict__ conv_b,
                    float* __restrict__ out)
{
  __shared__ __align__(16) unsigned short s_hi[4][HREG * HSTR];  // 19.0 KB, wave-private regions
  __shared__ __align__(16) char s_feat[4][4096];                 // 16 KB: feat stage (lin) / store stage (conv)

  const int raw = blockIdx.x;
  const int bid = (raw % 8) * XSPAN + (raw / 8);   // bijective XCD swizzle
  const int j    = bid % NJ;
  const int tile = (bid / NJ) % NTILES;
  const int b    = bid / (NJ * NTILES);
  const int nid  = c_name_ids[j];
  const int jp   = (j > 0) ? (j - 1) : 0;
  const int t0   = tile * TTILE;

  const int tid = threadIdx.x;
  const int wv = tid >> 6;        // wave 0..3
  const int l  = tid & 63;
  const int r  = l & 15;          // M/N index within fragment
  const int g  = l >> 4;          // k-slot group

  char* featc = s_feat[wv];               // wave-private
  unsigned short* hreg = s_hi[wv];        // wave-private h region (66 rows)
  const int R0 = t0 + wv * WROWS;         // wave's first out row (global time)

  const float* xj_base = x + ((size_t)b * T * NJ + j) * 32;
  const float* xp_base = x + ((size_t)b * T * NJ + jp) * 32;

  // Issue the 4 LDS-DMA loads for lin tile i (local h rows 16i..16i+15, i.e.
  // global time R0-1+16i+row). Each instruction a contiguous 1KB (8 full
  // lines); global source byte is inverse-XOR-swizzled so LDS holds the
  // swizzled layout (rule #21).
  auto issue_feat = [&](int i) {
#pragma unroll
    for (int j2 = 0; j2 < 2; ++j2) {
      const float* jb = j2 ? xp_base : xj_base;
#pragma unroll
      for (int hg = 0; hg < 2; ++hg) {
        const int row = hg * 8 + (l >> 3);
        int t = R0 - 1 + i * 16 + row;        // reflect padding in time
        if (t < 0) t = -t;
        if (t > T - 1) t = 2 * (T - 1) - t;
        const char* src = reinterpret_cast<const char*>(jb + (size_t)t * (NJ * 32))
                          + (((l & 7) * 16) ^ ((row & 7) << 4));
        __builtin_amdgcn_global_load_lds(
            (const __attribute__((address_space(1))) unsigned int*)src,
            (__attribute__((address_space(3))) unsigned int*)(&s_feat[wv][j2 * 2048 + hg * 1024]),
            16, 0, 0);
      }
    }
  };

  // ---- prologue: first tile in flight, then lin weight fragments ----
  issue_feat(0);

  short8_t blh[2][2], bll[2][2];
#pragma unroll
  for (int ks = 0; ks < 2; ++ks)
#pragma unroll
    for (int nt = 0; nt < 2; ++nt) {
      blh[ks][nt] = g_linfrag[nid][ks][nt][0][l];
      bll[ks][nt] = g_linfrag[nid][ks][nt][1][l];
    }
  const float lb0 = lin_b[nid * 32 + r];
  const float lb1 = lin_b[nid * 32 + r + 16];

  // ---------------- linear phase: h = relu(feat @ W + b) ----------------
  for (int i = 0; i < LT_W; ++i) {
    VM_FENCE();   // feat[i] landed (1st iter also drains weight loads)

    f32x4 a0[2], a1[2];
#pragma unroll
    for (int ks = 0; ks < 2; ++ks) {
      const char* fw = featc + ks * 2048 + r * 128;
      a0[ks] = *reinterpret_cast<const f32x4*>(fw + ((16 * g) ^ ((r & 7) << 4)));
      a1[ks] = *reinterpret_cast<const f32x4*>(fw + ((64 + 16 * g) ^ ((r & 7) << 4)));
    }
    WAVE_FENCE();                       // feat reads retired -> buffer reusable
    if (i + 1 < LT_W) issue_feat(i + 1);   // DMA overlaps cvt + MFMA below

    // R21: input hi-part only (RTZ top16); residual dropped (conv phase has
    // always dropped its input residual and passes).
    short8_t ah[2];
#pragma unroll
    for (int ks = 0; ks < 2; ++ks) {
#pragma unroll
      for (int e = 0; e < 8; ++e) {
        const float f = (e < 4) ? a0[ks][e] : a1[ks][e - 4];
        ah[ks][e] = (short)(unsigned short)(__builtin_bit_cast(uint32_t, f) >> 16);
      }
    }

#pragma unroll
    for (int nt = 0; nt < 2; ++nt) {
      const float lb = nt ? lb1 : lb0;
      f32x4 acc = {lb, lb, lb, lb};
#pragma unroll
      for (int ks = 0; ks < 2; ++ks) {
        acc = __builtin_amdgcn_mfma_f32_16x16x32_bf16(ah[ks], blh[ks][nt], acc, 0, 0, 0);
        acc = __builtin_amdgcn_mfma_f32_16x16x32_bf16(ah[ks], bll[ks][nt], acc, 0, 0, 0);
      }
      // C/D layout (m89): row = 4g+q, col = r
#pragma unroll
      for (int q = 0; q < 4; ++q) {
        const int hrow = i * 16 + 4 * g + q;
        if (hrow < HREG)   // only tile i=4's tail rows are out of range
          hreg[hrow * HSTR + r + 16 * nt] = f2bf(fmaxf(acc[q], 0.0f));
      }
    }
  }

  // ---- lin -> conv join is WAVE-LOCAL: drain own h ds_writes; no barrier.
  WAVE_FENCE();

  // ---- conv weight fragments (lin weights dead -> phase separation holds) ----
  short8_t bch[3][2], bcl[3][2];
#pragma unroll
  for (int k = 0; k < 3; ++k)
#pragma unroll
    for (int nt = 0; nt < 2; ++nt) {
      bch[k][nt] = g_convfrag[nid][k][nt][0][l];
      bcl[k][nt] = g_convfrag[nid][k][nt][1][l];
    }
  const float cb0 = conv_b[nid * 32 + r];
  const float cb1 = conv_b[nid * 32 + r + 16];

  float* st = reinterpret_cast<float*>(featc);   // alias: feat buffer dead in conv

  // ---------------- conv phase: y[t] = sum_k h[t+k-1] @ cw[k] + cb ----------------
  // Out rows R0+16ct+row; A-rows are wave-local h rows 16ct+r+k (max 65 < 66).
  for (int ct = 0; ct < CT_W; ++ct) {
    short8_t ah[3];
#pragma unroll
    for (int k = 0; k < 3; ++k) {
      const int arow = ct * 16 + r + k;
      const ushort4a u0 = *reinterpret_cast<const ushort4a*>(&hreg[arow * HSTR + 4 * g]);
      const ushort4a u1 = *reinterpret_cast<const ushort4a*>(&hreg[arow * HSTR + 16 + 4 * g]);
      short8_t hi8;
#pragma unroll
      for (int e = 0; e < 4; ++e) {
        hi8[e] = (short)u0[e];
        hi8[e + 4] = (short)u1[e];
      }
      ah[k] = hi8;
    }

    f32x4 accv[2];
#pragma unroll
    for (int nt = 0; nt < 2; ++nt) {
      const float cb = nt ? cb1 : cb0;
      f32x4 acc = {cb, cb, cb, cb};
#pragma unroll
      for (int k = 0; k < 3; ++k) {
        acc = __builtin_amdgcn_mfma_f32_16x16x32_bf16(ah[k], bch[k][nt], acc, 0, 0, 0);
        acc = __builtin_amdgcn_mfma_f32_16x16x32_bf16(ah[k], bcl[k][nt], acc, 0, 0, 0);
      }
      accv[nt] = acc;
    }

    // ---- wide-store epilogue: transpose acc through wave-private LDS ----
    WAVE_FENCE();   // WAR: previous tile's staging reads retired
#pragma unroll
    for (int nt = 0; nt < 2; ++nt)
#pragma unroll
      for (int q = 0; q < 4; ++q)
        st[(4 * g + q) * SSTR + r + 16 * nt] = accv[nt][q];
    WAVE_FENCE();   // RAW: staging writes visible to transposed reads

#pragma unroll
    for (int h2 = 0; h2 < 2; ++h2) {
      const int row = h2 * 8 + (l >> 3);          // 8-lane groups read one row
      const float* rp = st + row * SSTR + (l & 7) * 4;
      const f32x2 rd0 = *reinterpret_cast<const f32x2*>(rp);      // 8B reads keep
      const f32x2 rd1 = *reinterpret_cast<const f32x2*>(rp + 2);  // odd rows aligned
      f32x4 rd;
      rd[0] = rd0[0]; rd[1] = rd0[1]; rd[2] = rd1[0]; rd[3] = rd1[1];
      const int t = R0 + ct * 16 + row;
      // Nontemporal: out is write-once; do not evict the L2-resident x columns.
      __builtin_nontemporal_store(rd, reinterpret_cast<f32x4*>(
          out + ((size_t)(b * T + t) * NJ + j) * 32 + (l & 7) * 4));
    }
  }
}

extern "C" void kernel_launch(void* const* d_in, const int* in_sizes, int n_in,
                              void* d_out, int out_size, void* d_ws, size_t ws_size,
                              hipStream_t stream) {
  const float* x      = (const float*)d_in[0];
  const float* lin_w  = (const float*)d_in[1];
  const float* lin_b  = (const float*)d_in[2];
  const float* conv_w = (const float*)d_in[3];
  const float* conv_b = (const float*)d_in[4];
  float* out = (float*)d_out;

  prep_weights<<<dim3(NN), 64, 0, stream>>>(lin_w, conv_w);
  fused_rcb_mfma<<<dim3(NBLK), 256, 0, stream>>>(x, lin_b, conv_b, out);
}

// Round 13
// 77.054 us; speedup vs baseline: 1.8392x; 1.0481x over previous
//
#include <hip/hip_runtime.h>
#include <hip/hip_bf16.h>
#include <cstddef>
#include <cstdint>

typedef __attribute__((ext_vector_type(8))) short short8_t;   // 8 bf16 (4 VGPRs)
typedef __attribute__((ext_vector_type(4))) float f32x4;
typedef __attribute__((ext_vector_type(2))) float f32x2;
typedef unsigned short ushort4a __attribute__((ext_vector_type(4))); // 8B

// Per-wave fences: forbid compiler motion of memory ops and drain the HW
// queue. Cross-lane LDS deps and LDS-DMA writes are invisible to per-thread
// dependence analysis.
#define WAVE_FENCE()                                        \
  do {                                                      \
    asm volatile("s_waitcnt lgkmcnt(0)" ::: "memory");      \
    __builtin_amdgcn_sched_barrier(0);                      \
  } while (0)
#define VM_FENCE()                                          \
  do {                                                      \
    asm volatile("s_waitcnt vmcnt(0)" ::: "memory");        \
    __builtin_amdgcn_sched_barrier(0);                      \
  } while (0)

namespace {
constexpr int T = 2048;
constexpr int NB = 16;
constexpr int NJ = 53;
constexpr int NN = 18;              // names
constexpr int TTILE = 256;          // R16: per-block tax amortization; NT stores keep L2 reuse
constexpr int NTILES = T / TTILE;   // 8
constexpr int MT_LIN = 17;          // ceil(258/16) m-tiles for linear phase
constexpr int MT_CNV = 16;          // conv m-tiles
constexpr int HROWS = TTILE + 2;    // 258 h rows actually consumed by conv
constexpr int HSTR = 36;            // ushort stride per h row (72B, 8B-aligned rows)
// SSTR=38 (R15): g-stride 152B == 24 mod 32 dwords -> staging writes 2-way (free).
constexpr int SSTR = 38;            // f32 stride of store-staging tile (152B)
constexpr int NBLK = NB * NJ * NTILES;  // 6784
constexpr int XSPAN = NBLK / 8;         // 848 (bijective XCD swizzle)
}

__constant__ int c_name_ids[NJ] = {
    0,1,2,3,4,1,2,3,4,5,6,7,8,9,10,11,12,13,14,15,16,14,15,16,14,15,16,
    14,15,16,14,15,16,10,11,12,13,14,15,16,14,15,16,14,15,16,14,15,16,
    14,15,16,17};

// Precomputed weight fragments: [name][ks|k][nt][hi/lo][lane]
__device__ short8_t g_linfrag[NN][2][2][2][64];   // 147 KB
__device__ short8_t g_convfrag[NN][3][2][2][64];  // 221 KB

__device__ __forceinline__ unsigned short f2bf(float f) {
  return __builtin_bit_cast(unsigned short, __float2bfloat16(f));
}
__device__ __forceinline__ float bf2f(unsigned short u) {
  return __bfloat162float(__builtin_bit_cast(__hip_bfloat16, u));
}

// slot map: slot(g,e) -> k = 4g + (e&3) + 16*(e>>2); used identically for A and B
// fragments, so any true HW k-map yields a correct dot product.

__global__ __launch_bounds__(64)
void prep_weights(const float* __restrict__ lin_w,
                  const float* __restrict__ conv_w)
{
  const int n = blockIdx.x;
  const int l = threadIdx.x;
  const int r = l & 15;
  const int g = l >> 4;
#pragma unroll
  for (int ks = 0; ks < 2; ++ks)
#pragma unroll
    for (int nt = 0; nt < 2; ++nt) {
      short8_t hi8, lo8;
#pragma unroll
      for (int e = 0; e < 8; ++e) {
        const int kk = 4 * g + (e & 3) + 16 * (e >> 2);
        const float w = lin_w[((size_t)n * 64 + ks * 32 + kk) * 32 + r + 16 * nt];
        const unsigned short h = f2bf(w);
        hi8[e] = (short)h;
        lo8[e] = (short)f2bf(w - bf2f(h));
      }
      g_linfrag[n][ks][nt][0][l] = hi8;
      g_linfrag[n][ks][nt][1][l] = lo8;
    }
#pragma unroll
  for (int k = 0; k < 3; ++k)
#pragma unroll
    for (int nt = 0; nt < 2; ++nt) {
      short8_t hi8, lo8;
#pragma unroll
      for (int e = 0; e < 8; ++e) {
        const int i = 4 * g + (e & 3) + 16 * (e >> 2);
        const float w = conv_w[(((size_t)n * 32 + r + 16 * nt) * 32 + i) * 3 + k];
        const unsigned short h = f2bf(w);
        hi8[e] = (short)h;
        lo8[e] = (short)f2bf(w - bf2f(h));
      }
      g_convfrag[n][k][nt][0][l] = hi8;
      g_convfrag[n][k][nt][1][l] = lo8;
    }
}

// R25 = R21 verbatim (the session's verified best: 77.05us). Full structural
// ledger tested R13-R24; every remaining lever measured negative:
//   - transport: LDS-DMA staging beats direct global->VGPR (R17: -13us)
//   - occupancy: pinned ~16 waves/CU (R19/R20: more waves never materialize
//     or don't help); depth-2 pipeline at 3 blk/CU loses (R22: -5.9us)
//   - fusion of lin+conv weight sets spills (R14/R18/R19: WRITE_SIZE 2-4x)
//   - persistence breaks the j/j+1 L2 column reuse (R23: FETCH 110->290MB)
//   - barrier removal costs more in recompute than it saves (R24: +3.7us)
// Wins kept here: NT stores (L2 protection), TTILE=256 (tax amortization),
// SSTR=38 (staging bank fix), RTZ hi-only input cvt (VALU chain halved),
// LDS-DMA + source-side XOR swizzle, phase separation, (256,4) bounds.
__global__ __launch_bounds__(256, 4)
void fused_rcb_mfma(const float* __restrict__ x,
                    const float* __restrict__ lin_b,
                    const float* __restrict__ conv_b,
                    float* __restrict__ out)
{
  __shared__ __align__(16) unsigned short s_hi[HROWS * HSTR];  // 18.6 KB
  __shared__ __align__(16) char s_feat[4][4096];               // 16 KB: feat stage (lin) / store stage (conv)

  const int raw = blockIdx.x;
  const int bid = (raw % 8) * XSPAN + (raw / 8);   // bijective XCD swizzle
  const int j    = bid % NJ;
  const int tile = (bid / NJ) % NTILES;
  const int b    = bid / (NJ * NTILES);
  const int nid  = c_name_ids[j];
  const int jp   = (j > 0) ? (j - 1) : 0;
  const int t0   = tile * TTILE;

  const int tid = threadIdx.x;
  const int wv = tid >> 6;        // wave 0..3
  const int l  = tid & 63;
  const int r  = l & 15;          // M/N index within fragment
  const int g  = l >> 4;          // k-slot group

  char* featc = s_feat[wv];       // wave-private

  const float* xj_base = x + ((size_t)b * T * NJ + j) * 32;
  const float* xp_base = x + ((size_t)b * T * NJ + jp) * 32;

  // ---- linear weight fragments: coalesced 16B/lane loads from prep table ----
  short8_t blh[2][2], bll[2][2];
#pragma unroll
  for (int ks = 0; ks < 2; ++ks)
#pragma unroll
    for (int nt = 0; nt < 2; ++nt) {
      blh[ks][nt] = g_linfrag[nid][ks][nt][0][l];
      bll[ks][nt] = g_linfrag[nid][ks][nt][1][l];
    }
  const float lb0 = lin_b[nid * 32 + r];
  const float lb1 = lin_b[nid * 32 + r + 16];

  // Issue the 4 LDS-DMA loads for m-tile mt: 2 j x 2 groups of 8 rows, each
  // instruction a contiguous 1KB (8 full lines). Global source byte is
  // inverse-XOR-swizzled so LDS holds the swizzled layout (rule #21).
  auto issue_feat = [&](int mt) {
#pragma unroll
    for (int j2 = 0; j2 < 2; ++j2) {
      const float* jb = j2 ? xp_base : xj_base;
#pragma unroll
      for (int i = 0; i < 2; ++i) {
        const int row = i * 8 + (l >> 3);
        int t = t0 + mt * 16 + row - 1;       // reflect padding in time
        if (t < 0) t = -t;
        if (t > T - 1) t = 2 * (T - 1) - t;
        const char* src = reinterpret_cast<const char*>(jb + (size_t)t * (NJ * 32))
                          + (((l & 7) * 16) ^ ((row & 7) << 4));
        __builtin_amdgcn_global_load_lds(
            (const __attribute__((address_space(1))) unsigned int*)src,
            (__attribute__((address_space(3))) unsigned int*)(&s_feat[wv][j2 * 2048 + i * 1024]),
            16, 0, 0);
      }
    }
  };

  // ---------------- linear phase: h = relu(feat @ W + b) ----------------
  issue_feat(wv);
  for (int mt = wv; mt < MT_LIN; mt += 4) {
    VM_FENCE();   // feat[mt] fully landed in LDS (LDS-DMA tracked by vmcnt)

    // Fragment ds_reads first; cvt deferred until after next DMA is issued so
    // the DMA overlaps the cvt chain AND the MFMA block.
    f32x4 a0[2], a1[2];
#pragma unroll
    for (int ks = 0; ks < 2; ++ks) {
      const char* fw = featc + ks * 2048 + r * 128;
      a0[ks] = *reinterpret_cast<const f32x4*>(fw + ((16 * g) ^ ((r & 7) << 4)));
      a1[ks] = *reinterpret_cast<const f32x4*>(fw + ((64 + 16 * g) ^ ((r & 7) << 4)));
    }
    WAVE_FENCE();                       // feat reads retired -> buffer reusable
    if (mt + 4 < MT_LIN) issue_feat(mt + 4);   // DMA overlaps cvt + MFMA below

    // R21: input hi-part only (RTZ top16). Residual dropped -- the conv
    // phase has always dropped its input residual and passes.
    short8_t ah[2];
#pragma unroll
    for (int ks = 0; ks < 2; ++ks) {
#pragma unroll
      for (int e = 0; e < 8; ++e) {
        const float f = (e < 4) ? a0[ks][e] : a1[ks][e - 4];
        ah[ks][e] = (short)(unsigned short)(__builtin_bit_cast(uint32_t, f) >> 16);
      }
    }

#pragma unroll
    for (int nt = 0; nt < 2; ++nt) {
      const float lb = nt ? lb1 : lb0;
      f32x4 acc = {lb, lb, lb, lb};
#pragma unroll
      for (int ks = 0; ks < 2; ++ks) {
        acc = __builtin_amdgcn_mfma_f32_16x16x32_bf16(ah[ks], blh[ks][nt], acc, 0, 0, 0);
        acc = __builtin_amdgcn_mfma_f32_16x16x32_bf16(ah[ks], bll[ks][nt], acc, 0, 0, 0);
      }
      // C/D layout (m89): row = 4g+q, col = r
#pragma unroll
      for (int q = 0; q < 4; ++q) {
        const int hrow = mt * 16 + 4 * g + q;
        if (hrow < HROWS)   // only mt=16 tail rows are out of range
          s_hi[hrow * HSTR + r + 16 * nt] = f2bf(fmaxf(acc[q], 0.0f));
      }
    }
  }

  // ---- conv weight fragments: issue BEFORE the barrier so the global-load
  // latency hides under the slowest wave's lin tail ----
  short8_t bch[3][2], bcl[3][2];
#pragma unroll
  for (int k = 0; k < 3; ++k)
#pragma unroll
    for (int nt = 0; nt < 2; ++nt) {
      bch[k][nt] = g_convfrag[nid][k][nt][0][l];
      bcl[k][nt] = g_convfrag[nid][k][nt][1][l];
    }
  const float cb0 = conv_b[nid * 32 + r];
  const float cb1 = conv_b[nid * 32 + r + 16];

  __syncthreads();

  float* st = reinterpret_cast<float*>(featc);   // alias: feat buffer dead in conv

  // ---------------- conv phase: y[t] = sum_k h[t+k-1] @ cw[k] + cb ----------------
  for (int mt = wv; mt < MT_CNV; mt += 4) {
    const int m0 = mt * 16;
    short8_t ah[3];
#pragma unroll
    for (int k = 0; k < 3; ++k) {
      const int arow = m0 + r + k;
      const ushort4a u0 = *reinterpret_cast<const ushort4a*>(&s_hi[arow * HSTR + 4 * g]);
      const ushort4a u1 = *reinterpret_cast<const ushort4a*>(&s_hi[arow * HSTR + 16 + 4 * g]);
      short8_t hi8;
#pragma unroll
      for (int e = 0; e < 4; ++e) {
        hi8[e] = (short)u0[e];
        hi8[e + 4] = (short)u1[e];
      }
      ah[k] = hi8;
    }

    f32x4 accv[2];
#pragma unroll
    for (int nt = 0; nt < 2; ++nt) {
      const float cb = nt ? cb1 : cb0;
      f32x4 acc = {cb, cb, cb, cb};
#pragma unroll
      for (int k = 0; k < 3; ++k) {
        acc = __builtin_amdgcn_mfma_f32_16x16x32_bf16(ah[k], bch[k][nt], acc, 0, 0, 0);
        acc = __builtin_amdgcn_mfma_f32_16x16x32_bf16(ah[k], bcl[k][nt], acc, 0, 0, 0);
      }
      accv[nt] = acc;
    }

    // ---- wide-store epilogue: transpose acc through wave-private LDS ----
    WAVE_FENCE();   // WAR: previous m-tile's staging reads retired
#pragma unroll
    for (int nt = 0; nt < 2; ++nt)
#pragma unroll
      for (int q = 0; q < 4; ++q)
        st[(4 * g + q) * SSTR + r + 16 * nt] = accv[nt][q];
    WAVE_FENCE();   // RAW: staging writes visible to transposed reads

#pragma unroll
    for (int h2 = 0; h2 < 2; ++h2) {
      const int row = h2 * 8 + (l >> 3);          // 8-lane groups read one row
      const float* rp = st + row * SSTR + (l & 7) * 4;
      const f32x2 rd0 = *reinterpret_cast<const f32x2*>(rp);      // 8B reads keep
      const f32x2 rd1 = *reinterpret_cast<const f32x2*>(rp + 2);  // odd rows aligned
      f32x4 rd;
      rd[0] = rd0[0]; rd[1] = rd0[1]; rd[2] = rd1[0]; rd[3] = rd1[1];
      const int t = t0 + m0 + row;
      // Nontemporal: out is write-once; do not evict the L2-resident x columns.
      __builtin_nontemporal_store(rd, reinterpret_cast<f32x4*>(
          out + ((size_t)(b * T + t) * NJ + j) * 32 + (l & 7) * 4));
    }
  }
}

extern "C" void kernel_launch(void* const* d_in, const int* in_sizes, int n_in,
                              void* d_out, int out_size, void* d_ws, size_t ws_size,
                              hipStream_t stream) {
  const float* x      = (const float*)d_in[0];
  const float* lin_w  = (const float*)d_in[1];
  const float* lin_b  = (const float*)d_in[2];
  const float* conv_w = (const float*)d_in[3];
  const float* conv_b = (const float*)d_in[4];
  float* out = (float*)d_out;

  prep_weights<<<dim3(NN), 64, 0, stream>>>(lin_w, conv_w);
  fused_rcb_mfma<<<dim3(NBLK), 256, 0, stream>>>(x, lin_b, conv_b, out);
}